// Round 9
// baseline (136.145 us; speedup 1.0000x reference)
//
#include <hip/hip_runtime.h>
#include <hip/hip_bf16.h>

// ---------------------------------------------------------------------------
// EuclideanDeconf: out[b,c] = (2*dot(x[b],W[c]) - ||x[b]||^2 - ||W[c]||^2) / D
// R15: barrier-free gemm. All six prior structures lockstep the block's waves
// with s_barrier every K-tile. R15 gives each wave a PRIVATE LDS ring (3 bufs
// x 8KB: its own 64 A-rows + 64 B-rows), so global_load_lds completion is
// guaranteed by the wave's own vmcnt alone -> ZERO barriers in the K-loop;
// 4 independent wave pipelines per CU, each PD=2-tiles deep (WAITV(8), never
// drains until the 2 peeled tail iters). Staging fetches each chunk twice
// (2 waves share a panel) -- L2-served. Swizzle identical algebra (verified:
// source pre-swz ((l&3)^((l>>3)&3)) and read swz both survive the 64-row
// wave-local layout). KSPLIT=1 + fused epilogue kept from R14.
// 128x128xBK64, 256 thr (4 waves 2x2, wave=64x64), grid (32,8)=256.
// ---------------------------------------------------------------------------

typedef float f32x4 __attribute__((ext_vector_type(4)));
typedef float f32x2 __attribute__((ext_vector_type(2)));
typedef float f32x16 __attribute__((ext_vector_type(16)));
typedef int i32x4 __attribute__((ext_vector_type(4)));
typedef int i32x8 __attribute__((ext_vector_type(8)));

#define BDIM 4096
#define DDIM 4096
#define CDIM 1024
#define TM 128
#define TN 128
#define BK 64
#define NIT (DDIM / BK)              // 64
#define SCALE 32.0f
#define INV_SS (1.0f/1024.0f)

#define WAITV(N) asm volatile("s_waitcnt vmcnt(" #N ")" ::: "memory")

// One WAVE per row: fp32 row -> fp8(e4m3, x SCALE) row + fp32 sum-of-squares
// (of the UNSCALED values).
__global__ __launch_bounds__(256) void cvt_rowsq(
    const float* __restrict__ x, const float* __restrict__ W,
    unsigned char* __restrict__ xb, unsigned char* __restrict__ wb,
    float* __restrict__ xsq, float* __restrict__ wsq)
{
    const int lane = threadIdx.x & 63;
    const int row = blockIdx.x * 4 + (threadIdx.x >> 6);

    const float* src;
    unsigned char* dst;
    float* sq;
    if (row < BDIM) {
        src = x + (size_t)row * DDIM;
        dst = xb + (size_t)row * DDIM;
        sq = xsq + row;
    } else {
        int r = row - BDIM;
        src = W + (size_t)r * DDIM;
        dst = wb + (size_t)r * DDIM;
        sq = wsq + r;
    }

    const float4* s4 = (const float4*)src;
    unsigned int* d4 = (unsigned int*)dst;
    float a = 0.f;
    #pragma unroll
    for (int s = 0; s < DDIM / 4 / 64; ++s) {
        float4 f = s4[lane + 64 * s];
        a += f.x * f.x + f.y * f.y + f.z * f.z + f.w * f.w;
        unsigned int p = 0;
        p = __builtin_amdgcn_cvt_pk_fp8_f32(f.x * SCALE, f.y * SCALE, p, false);
        p = __builtin_amdgcn_cvt_pk_fp8_f32(f.z * SCALE, f.w * SCALE, p, true);
        d4[lane + 64 * s] = p;
    }
    #pragma unroll
    for (int off = 32; off > 0; off >>= 1) a += __shfl_down(a, off);
    if (lane == 0) *sq = a;
}

// --- GEMM + fused epilogue, barrier-free ---
// Wave-private LDS: wave w at sm + w*24576; buf q at +q*8192:
//   A[64][64] fp8 at +0, B[64][64] at +4096.
// Swizzle: 16B chunk (local row m, chunk c) at slot (m, c ^ ((m>>1)&3)).
// Staging: 8 gloads/wave/tile (4 A + 4 B, 16 rows each). Lane l covers local
// row 16i+(l>>2), slot l&3 <- global chunk (l&3)^((l>>3)&3)  [(m>>1)&3 ==
// (l>>3)&3 since 16i == 0 mod 4]. DMA dest wave-uniform; writes lane*16.
// Frag reads: lane l: local row (l&31), chunks c0=(l>>5)*2, c0^1 swizzled
// (s=((l&31)>>1)&3) -> two ds_read_b128; conflict-free (verified R12 algebra).

__device__ __forceinline__ i32x8 cat8(i32x4 lo, i32x4 hi) {
    return __builtin_shufflevector(lo, hi, 0, 1, 2, 3, 4, 5, 6, 7);
}

#define MXMFMA(A, Bv, C)                                                  \
    __builtin_amdgcn_mfma_scale_f32_32x32x64_f8f6f4(                      \
        (A), (Bv), (C), 0, 0, 0, 0x7F7F7F7F, 0, 0x7F7F7F7F)

#define GLOAD16(gp, lp)                                                   \
    __builtin_amdgcn_global_load_lds(                                     \
        (const __attribute__((address_space(1))) void*)(gp),              \
        (__attribute__((address_space(3))) void*)(lp), 16, 0, 0)

__global__ __launch_bounds__(256) void gemm_eucl(
    const unsigned char* __restrict__ xb,   // [B, D] fp8
    const unsigned char* __restrict__ wb,   // [C, D] fp8
    const float* __restrict__ xsq, const float* __restrict__ wsq,
    float* __restrict__ out)                // [B, C] fp32
{
    __shared__ unsigned char sm[4 * 3 * 8192];   // 96 KB

    const int tid = threadIdx.x;
    const int lane = tid & 63;
    const int w = tid >> 6;                 // wave 0..3
    const int wr = w >> 1;                  // 0..1  (M half: 64 rows)
    const int wc = w & 1;                   // 0..1  (N half: 64 rows)
    const int bm = blockIdx.x * TM;
    const int bn = blockIdx.y * TN;

    unsigned char* wbase = sm + w * 24576;

    // ---- staging: per-lane pre-swizzled global sources (coalesced) ----
    const int lr = lane >> 2;                                // 0..15
    const int schunk = ((lane & 3) ^ ((lane >> 3) & 3)) * 16;
    const unsigned char* gA[4];
    const unsigned char* gB[4];
    #pragma unroll
    for (int i = 0; i < 4; ++i) {
        gA[i] = xb + (size_t)(bm + wr * 64 + 16 * i + lr) * DDIM + schunk;
        gB[i] = wb + (size_t)(bn + wc * 64 + 16 * i + lr) * DDIM + schunk;
    }

#define STAGE(q, t)                                                       \
    do {                                                                  \
        _Pragma("unroll")                                                 \
        for (int i = 0; i < 4; ++i) {                                     \
            GLOAD16(gA[i] + (t) * BK, wbase + (q) * 8192 + i * 1024);     \
            GLOAD16(gB[i] + (t) * BK, wbase + (q) * 8192 + 4096 + i * 1024); \
        }                                                                 \
    } while (0)

    // ---- fragment read bases (swizzled, wave-local) ----
    const int s_rd = ((lane & 31) >> 1) & 3;
    const int c0s = ((lane >> 5) * 2) ^ s_rd;
    const unsigned char* aR0 = wbase + (lane & 31) * 64 + c0s * 16;
    const unsigned char* aR1 = wbase + (lane & 31) * 64 + (c0s ^ 1) * 16;
    const unsigned char* bR0 = aR0 + 4096;
    const unsigned char* bR1 = aR1 + 4096;

    f32x16 acc[4] = {};   // [i 0..1][j 0..1] -> acc[i*2+j]

#define COMPUTE(qo)                                                       \
    do {                                                                  \
        i32x8 fb0 = cat8(*(const i32x4*)(bR0 + (qo)),                     \
                         *(const i32x4*)(bR1 + (qo)));                    \
        i32x8 fb1 = cat8(*(const i32x4*)(bR0 + (qo) + 2048),              \
                         *(const i32x4*)(bR1 + (qo) + 2048));             \
        i32x8 fa0 = cat8(*(const i32x4*)(aR0 + (qo)),                     \
                         *(const i32x4*)(aR1 + (qo)));                    \
        i32x8 fa1 = cat8(*(const i32x4*)(aR0 + (qo) + 2048),              \
                         *(const i32x4*)(aR1 + (qo) + 2048));             \
        __builtin_amdgcn_s_setprio(1);                                    \
        acc[0] = MXMFMA(fa0, fb0, acc[0]);                                \
        acc[1] = MXMFMA(fa0, fb1, acc[1]);                                \
        acc[2] = MXMFMA(fa1, fb0, acc[2]);                                \
        acc[3] = MXMFMA(fa1, fb1, acc[3]);                                \
        __builtin_amdgcn_s_setprio(0);                                    \
    } while (0)

    // ---- prologue: tiles 0,1 (16 loads in flight, wave-private) ----
    STAGE(0, 0);
    STAGE(1, 1);

    // barrier-free main loop: WAITV(8) retires tile t (own loads, own LDS);
    // tile t+1's 8 stay flying; stage t+2 into buf (t-1)%3 (reads consumed
    // by tile t-1's MFMAs earlier in this wave's program order).
    #pragma unroll 6
    for (int t = 0; t < 60; ++t) {
        WAITV(8);
        STAGE((t + 2) % 3, t + 2);
        COMPUTE((t % 3) * 8192);
    }
    // t=60,61 (stage 62,63), then peeled tail
    WAITV(8); STAGE(2, 62); COMPUTE(0 * 8192);           // t=60
    WAITV(8); STAGE(0, 63); COMPUTE(1 * 8192);           // t=61
    WAITV(8); COMPUTE(2 * 8192);                         // t=62
    WAITV(0); COMPUTE(0 * 8192);                         // t=63

    // ---- fused epilogue ----
    // 32x32 C/D layout: col = lane&31, row = (reg&3)+8*(reg>>2)+4*(lane>>5).
    const float c1m = 2.0f * INV_SS / (float)DDIM;
    const float c2 = 1.0f / (float)DDIM;
    const int gn0 = bn + wc * 64 + (lane & 31);
    const int gm_b = bm + wr * 64 + (lane >> 5) * 4;
    const float wv0 = wsq[gn0];
    const float wv1 = wsq[gn0 + 32];
    #pragma unroll
    for (int i = 0; i < 2; ++i)
        #pragma unroll
        for (int g = 0; g < 4; ++g)
            #pragma unroll
            for (int r = 0; r < 4; ++r) {
                const int gm = gm_b + i * 32 + g * 8 + r;
                const float xs = xsq[gm];
                out[(size_t)gm * CDIM + gn0] =
                    acc[i * 2 + 0][g * 4 + r] * c1m - (xs + wv0) * c2;
                out[(size_t)gm * CDIM + gn0 + 32] =
                    acc[i * 2 + 1][g * 4 + r] * c1m - (xs + wv1) * c2;
            }
#undef STAGE
#undef COMPUTE
}

// --- Fallback: naive fp32 (any ws) ---
__global__ void fallback_kernel(const float* __restrict__ x, const float* __restrict__ W,
                                float* __restrict__ out)
{
    int c = blockIdx.x * blockDim.x + threadIdx.x;
    int b = blockIdx.y;
    if (c >= CDIM) return;
    const float* xr = x + (size_t)b * DDIM;
    const float* wr = W + (size_t)c * DDIM;
    float xs = 0.f, ws = 0.f, cr = 0.f;
    for (int d = 0; d < DDIM; ++d) {
        float xv = xr[d], wv = wr[d];
        xs += xv * xv; ws += wv * wv; cr += xv * wv;
    }
    out[(size_t)b * CDIM + c] = (2.0f * cr - xs - ws) / (float)DDIM;
}

extern "C" void kernel_launch(void* const* d_in, const int* in_sizes, int n_in,
                              void* d_out, int out_size, void* d_ws, size_t ws_size,
                              hipStream_t stream) {
    const float* x = (const float*)d_in[0];   // [B, D] fp32
    const float* W = (const float*)d_in[1];   // [C, D] fp32
    float* out = (float*)d_out;               // [B, C] fp32

    size_t need = (size_t)(BDIM + CDIM) * DDIM                 // fp8 inputs 20 MB
                + (size_t)(BDIM + CDIM) * sizeof(float);       // norms
    if (ws_size < need) {
        fallback_kernel<<<dim3(CDIM / 256, BDIM), 256, 0, stream>>>(x, W, out);
        return;
    }

    unsigned char* xb = (unsigned char*)d_ws;              // 16 MB
    unsigned char* wb = xb + (size_t)BDIM * DDIM;          // 4 MB
    float* xsq = (float*)(wb + (size_t)CDIM * DDIM);       // 16 KB
    float* wsq = xsq + BDIM;                               // 4 KB

    cvt_rowsq<<<(BDIM + CDIM) / 4, 256, 0, stream>>>(x, W, xb, wb, xsq, wsq);
    gemm_eucl<<<dim3(BDIM / TM, CDIM / TN), 256, 0, stream>>>(xb, wb, xsq, wsq, out);
}